// Round 1
// baseline (462.817 us; speedup 1.0000x reference)
//
#include <hip/hip_runtime.h>
#include <math.h>

#define ROWS 16384
#define COLS 4096
#define BLOCK 256
#define ELEMS_PER_THREAD 16  // COLS / BLOCK

__global__ void zero_ws_kernel(double* acc, unsigned long long* cnt) {
    if (threadIdx.x == 0) {
        acc[0] = 0.0;
        cnt[0] = 0ull;
    }
}

__global__ __launch_bounds__(BLOCK) void row_loss_kernel(
        const float* __restrict__ logits,
        const int* __restrict__ targets,
        double* __restrict__ acc,
        unsigned long long* __restrict__ cnt) {
    const int tid = threadIdx.x;
    const int row = blockIdx.x;
    const size_t base = (size_t)row * COLS;

    const float4* lg4 = reinterpret_cast<const float4*>(logits + base);
    const int4*   tg4 = reinterpret_cast<const int4*>(targets + base);

    // Stage the row in registers: 4 passes of float4/int4, coalesced.
    float v[ELEMS_PER_THREAD];
    unsigned posmask = 0u;  // bit j set => target == 1
    unsigned negmask = 0u;  // bit j set => target == 0
    #pragma unroll
    for (int p = 0; p < 4; ++p) {
        float4 l = lg4[tid + p * BLOCK];
        int4   t = tg4[tid + p * BLOCK];
        v[p * 4 + 0] = l.x; v[p * 4 + 1] = l.y;
        v[p * 4 + 2] = l.z; v[p * 4 + 3] = l.w;
        posmask |= (t.x == 1 ? 1u : 0u) << (p * 4 + 0);
        posmask |= (t.y == 1 ? 1u : 0u) << (p * 4 + 1);
        posmask |= (t.z == 1 ? 1u : 0u) << (p * 4 + 2);
        posmask |= (t.w == 1 ? 1u : 0u) << (p * 4 + 3);
        negmask |= (t.x == 0 ? 1u : 0u) << (p * 4 + 0);
        negmask |= (t.y == 0 ? 1u : 0u) << (p * 4 + 1);
        negmask |= (t.z == 0 ? 1u : 0u) << (p * 4 + 2);
        negmask |= (t.w == 0 ? 1u : 0u) << (p * 4 + 3);
    }

    __shared__ float sred[4];   // per-wave partials (4 waves of 64)
    __shared__ float sred2[4];
    __shared__ double sds[4];
    __shared__ int   sci[4];
    const int wave = tid >> 6;
    const int lane = tid & 63;

    // ---- Pass 1: max over negative logits ----
    float m = -INFINITY;
    #pragma unroll
    for (int j = 0; j < ELEMS_PER_THREAD; ++j)
        if ((negmask >> j) & 1u) m = fmaxf(m, v[j]);
    #pragma unroll
    for (int off = 32; off; off >>= 1)
        m = fmaxf(m, __shfl_xor(m, off));
    if (lane == 0) sred[wave] = m;
    __syncthreads();
    m = fmaxf(fmaxf(sred[0], sred[1]), fmaxf(sred[2], sred[3]));

    // ---- Pass 2: sum of exp(v - m) over negative logits ----
    float s = 0.0f;
    #pragma unroll
    for (int j = 0; j < ELEMS_PER_THREAD; ++j)
        if ((negmask >> j) & 1u) s += __expf(v[j] - m);
    #pragma unroll
    for (int off = 32; off; off >>= 1)
        s += __shfl_xor(s, off);
    if (lane == 0) sred2[wave] = s;
    __syncthreads();
    s = (sred2[0] + sred2[1]) + (sred2[2] + sred2[3]);

    // neg_lse = m + log(s); if no negatives, m = -inf and s = 0 -> -inf.
    float neg_lse = m + __logf(s);

    // ---- Pass 3: softplus(neg_lse - v) over positive logits ----
    float local = 0.0f;
    int c = __popc(posmask);
    #pragma unroll
    for (int j = 0; j < ELEMS_PER_THREAD; ++j) {
        if ((posmask >> j) & 1u) {
            float x = neg_lse - v[j];
            // softplus(x) = max(x,0) + log1p(exp(-|x|)); x = -inf -> 0 (no NaN)
            float sp = fmaxf(x, 0.0f) + log1pf(__expf(-fabsf(x)));
            local += sp;
        }
    }
    #pragma unroll
    for (int off = 32; off; off >>= 1) {
        local += __shfl_xor(local, off);
        c     += __shfl_xor(c, off);
    }
    if (lane == 0) { sds[wave] = (double)local; sci[wave] = c; }
    __syncthreads();

    if (tid == 0) {
        double t = (sds[0] + sds[1]) + (sds[2] + sds[3]);
        unsigned long long cc =
            (unsigned long long)(sci[0] + sci[1] + sci[2] + sci[3]);
        atomicAdd(acc, t);
        atomicAdd(cnt, cc);
    }
}

__global__ void finalize_kernel(const double* acc, const unsigned long long* cnt,
                                float* out) {
    if (threadIdx.x == 0) {
        unsigned long long c = cnt[0];
        out[0] = (c > 0) ? (float)(acc[0] / (double)c) : 0.0f;
    }
}

extern "C" void kernel_launch(void* const* d_in, const int* in_sizes, int n_in,
                              void* d_out, int out_size, void* d_ws, size_t ws_size,
                              hipStream_t stream) {
    const float* logits  = (const float*)d_in[0];
    const int*   targets = (const int*)d_in[1];
    float* out = (float*)d_out;

    double* acc = (double*)d_ws;
    unsigned long long* cnt = (unsigned long long*)((char*)d_ws + sizeof(double));

    zero_ws_kernel<<<1, 64, 0, stream>>>(acc, cnt);
    row_loss_kernel<<<ROWS, BLOCK, 0, stream>>>(logits, targets, acc, cnt);
    finalize_kernel<<<1, 64, 0, stream>>>(acc, cnt, out);
}

// Round 2
// 104.843 us; speedup vs baseline: 4.4144x; 4.4144x over previous
//
#include <hip/hip_runtime.h>
#include <math.h>

#define ROWS 16384
#define COLS 4096
#define BLOCK 256
#define EPT 16  // COLS / BLOCK

// Stage 1: one block per row -> partial (sum, count) written to workspace.
// No atomics anywhere.
__global__ __launch_bounds__(BLOCK) void row_loss_kernel(
        const float* __restrict__ logits,
        const int* __restrict__ targets,
        double* __restrict__ part_sum,
        int* __restrict__ part_cnt) {
    const int tid = threadIdx.x;
    const int row = blockIdx.x;
    const size_t base = (size_t)row * COLS;

    const float4* lg4 = reinterpret_cast<const float4*>(logits + base);
    const int4*   tg4 = reinterpret_cast<const int4*>(targets + base);

    // Stage the row in registers, coalesced float4/int4.
    float v[EPT];
    unsigned posmask = 0u;  // bit j => target == 1
    unsigned negmask = 0u;  // bit j => target == 0
    #pragma unroll
    for (int p = 0; p < 4; ++p) {
        float4 l = lg4[tid + p * BLOCK];
        int4   t = tg4[tid + p * BLOCK];
        v[p * 4 + 0] = l.x; v[p * 4 + 1] = l.y;
        v[p * 4 + 2] = l.z; v[p * 4 + 3] = l.w;
        posmask |= (t.x == 1 ? 1u : 0u) << (p * 4 + 0);
        posmask |= (t.y == 1 ? 1u : 0u) << (p * 4 + 1);
        posmask |= (t.z == 1 ? 1u : 0u) << (p * 4 + 2);
        posmask |= (t.w == 1 ? 1u : 0u) << (p * 4 + 3);
        negmask |= (t.x == 0 ? 1u : 0u) << (p * 4 + 0);
        negmask |= (t.y == 0 ? 1u : 0u) << (p * 4 + 1);
        negmask |= (t.z == 0 ? 1u : 0u) << (p * 4 + 2);
        negmask |= (t.w == 0 ? 1u : 0u) << (p * 4 + 3);
    }

    __shared__ float  sredf[4];
    __shared__ double sredd[4];
    __shared__ int    sredi[4];
    const int wave = tid >> 6;
    const int lane = tid & 63;

    // ---- Pass 1: max over negative logits ----
    float m = -INFINITY;
    #pragma unroll
    for (int j = 0; j < EPT; ++j)
        if ((negmask >> j) & 1u) m = fmaxf(m, v[j]);
    #pragma unroll
    for (int off = 32; off; off >>= 1)
        m = fmaxf(m, __shfl_xor(m, off));
    if (lane == 0) sredf[wave] = m;
    __syncthreads();
    m = fmaxf(fmaxf(sredf[0], sredf[1]), fmaxf(sredf[2], sredf[3]));

    // ---- Pass 2: sum exp(v - m) over negatives ----
    float s = 0.0f;
    #pragma unroll
    for (int j = 0; j < EPT; ++j) {
        float e = __expf(v[j] - m);           // may be inf for positives; masked out
        s += ((negmask >> j) & 1u) ? e : 0.0f;
    }
    #pragma unroll
    for (int off = 32; off; off >>= 1)
        s += __shfl_xor(s, off);
    __syncthreads();  // sredf reuse hazard guard
    if (lane == 0) sredf[wave] = s;
    __syncthreads();
    s = (sredf[0] + sredf[1]) + (sredf[2] + sredf[3]);

    // neg_lse; no negatives -> m=-inf, s=0 -> -inf (softplus then yields 0).
    float neg_lse = m + __logf(s);

    // ---- Pass 3: softplus(neg_lse - v) over positives ----
    float local = 0.0f;
    int   c = __popc(posmask);
    #pragma unroll
    for (int j = 0; j < EPT; ++j) {
        float x  = neg_lse - v[j];
        float sp = fmaxf(x, 0.0f) + __logf(1.0f + __expf(-fabsf(x)));
        local += ((posmask >> j) & 1u) ? sp : 0.0f;
    }
    #pragma unroll
    for (int off = 32; off; off >>= 1) {
        local += __shfl_xor(local, off);
        c     += __shfl_xor(c, off);
    }
    if (lane == 0) { sredd[wave] = (double)local; sredi[wave] = c; }
    __syncthreads();

    if (tid == 0) {
        part_sum[row] = (sredd[0] + sredd[1]) + (sredd[2] + sredd[3]);
        part_cnt[row] = (sredi[0] + sredi[1]) + (sredi[2] + sredi[3]);
    }
}

// Stage 2: reduce 16384 partials in one block, write the mean.
__global__ __launch_bounds__(1024) void reduce_kernel(
        const double* __restrict__ part_sum,
        const int* __restrict__ part_cnt,
        float* __restrict__ out) {
    const int tid  = threadIdx.x;
    const int wave = tid >> 6;
    const int lane = tid & 63;

    double s = 0.0;
    long long c = 0;
    for (int i = tid; i < ROWS; i += 1024) {
        s += part_sum[i];
        c += part_cnt[i];
    }
    #pragma unroll
    for (int off = 32; off; off >>= 1) {
        s += __shfl_xor(s, off);
        c += __shfl_xor(c, off);
    }
    __shared__ double sd[16];
    __shared__ long long sc[16];
    if (lane == 0) { sd[wave] = s; sc[wave] = c; }
    __syncthreads();
    if (tid == 0) {
        double ts = 0.0;
        long long tc = 0;
        #pragma unroll
        for (int w = 0; w < 16; ++w) { ts += sd[w]; tc += sc[w]; }
        out[0] = (tc > 0) ? (float)(ts / (double)tc) : 0.0f;
    }
}

extern "C" void kernel_launch(void* const* d_in, const int* in_sizes, int n_in,
                              void* d_out, int out_size, void* d_ws, size_t ws_size,
                              hipStream_t stream) {
    const float* logits  = (const float*)d_in[0];
    const int*   targets = (const int*)d_in[1];
    float* out = (float*)d_out;

    double* part_sum = (double*)d_ws;                       // 16384 * 8 B
    int*    part_cnt = (int*)((char*)d_ws + ROWS * sizeof(double));  // 16384 * 4 B

    row_loss_kernel<<<ROWS, BLOCK, 0, stream>>>(logits, targets, part_sum, part_cnt);
    reduce_kernel<<<1, 1024, 0, stream>>>(part_sum, part_cnt, out);
}